// Round 12
// baseline (712.011 us; speedup 1.0000x reference)
//
#include <hip/hip_runtime.h>
#include <math.h>

typedef _Float16 f16;
typedef __attribute__((ext_vector_type(8))) _Float16 f16x8;
typedef __attribute__((ext_vector_type(4))) float f32x4;
typedef __attribute__((ext_vector_type(16))) float f32x16;

#define LPOS 4096      // 64*64 positions / patches
#define KPAT 576       // 64ch * 3*3 patch
#define RPAT 2048      // 128ch * 4*4 raw patch
#define PPAD 20736     // 144*144 padded positions for ybT
#define ROWS 18432     // elems per padded row: 16 chunks * 144 x * 8

#define GLDS(g, l) __builtin_amdgcn_global_load_lds( \
    (const __attribute__((address_space(1))) void*)(g), \
    (__attribute__((address_space(3))) void*)(l), 16, 0, 0)

// ---------------------------------------------------------------------------
// Ph[pos][576] = fp16 3x3x64 patches of x2[b] (zero pad 1); rnorm[pos]
__global__ __launch_bounds__(64) void build_P_norm(const float* __restrict__ x2b,
                                                   f16* __restrict__ Ph,
                                                   float* __restrict__ rnorm) {
    int pos = blockIdx.x;
    int u = pos >> 6, v = pos & 63;
    int tid = threadIdx.x;
    float ss = 0.f;
    for (int k = tid; k < KPAT; k += 64) {
        int c = k / 9, r9 = k % 9;
        int di = r9 / 3, dj = r9 % 3;
        int yy = u + di - 1, xx = v + dj - 1;
        float val = 0.f;
        if (yy >= 0 && yy < 64 && xx >= 0 && xx < 64)
            val = x2b[c * 4096 + yy * 64 + xx];
        Ph[pos * KPAT + k] = (f16)val;
        ss += val * val;
    }
#pragma unroll
    for (int off = 32; off; off >>= 1) ss += __shfl_xor(ss, off, 64);
    if (tid == 0) rnorm[pos] = 1.f / fmaxf(sqrtf(ss), 1e-4f);
}

// ---------------------------------------------------------------------------
// All 4 batches in one launch: block b compacts mask[b] -> cidx[b], nk[b]
__global__ __launch_bounds__(256) void compact_mask_all(const float* __restrict__ mask,
                                                        int* __restrict__ cidx_all,
                                                        int* __restrict__ nk_all) {
    int b = blockIdx.x;
    const float* maskb = mask + (size_t)b * 16384;
    int* cidx = cidx_all + b * 4352;
    int* nk = nk_all + b * 2;
    int tid = threadIdx.x;
    int keep[16];
    int cnt = 0;
#pragma unroll
    for (int e = 0; e < 16; ++e) {
        int pos = tid * 16 + e;
        int pu = pos >> 6, pv = pos & 63;
        float s = 0.f;
        for (int t = 0; t < 4; ++t)
            for (int w = 0; w < 4; ++w) {
                int yy = 2 * pu - 1 + t, xx = 2 * pv - 1 + w;
                if (yy >= 0 && yy < 128 && xx >= 0 && xx < 128)
                    s += maskb[yy * 128 + xx];
            }
        keep[e] = (s == 0.f) ? 1 : 0;
        cnt += keep[e];
    }
    __shared__ int ps[256];
    ps[tid] = cnt;
    __syncthreads();
    for (int off = 1; off < 256; off <<= 1) {
        int v = (tid >= off) ? ps[tid - off] : 0;
        __syncthreads();
        ps[tid] += v;
        __syncthreads();
    }
    int total = ps[255];
    int base = ps[tid] - cnt;   // exclusive prefix
#pragma unroll
    for (int e = 0; e < 16; ++e)
        if (keep[e]) cidx[base++] = tid * 16 + e;
    for (int i = total + tid; i < 4352; i += 256) cidx[i] = 0;
    if (tid == 0) { nk[0] = total; nk[1] = (total + 31) & ~31; }
}

// ---------------------------------------------------------------------------
// Zero the 8-wide halo of the padded chunk-major ybT buffer (all 4 batches)
__global__ __launch_bounds__(256) void zero_halo(f16* __restrict__ ybTp) {
    int idx = blockIdx.x * 256 + threadIdx.x;
    int b = idx / 331776; if (b >= 4) return;
    int rem = idx % 331776;                     // 144*144*16
    int q = rem & 15, pos = rem >> 4;
    int yy = pos / 144, xx = pos % 144;
    if (yy >= 8 && yy < 136 && xx >= 8 && xx < 136) return;
    *(f16x8*)(ybTp + (size_t)b * PPAD * 128 + (size_t)yy * ROWS + q * 1152 + xx * 8) = (f16x8){};
}

// ---------------------------------------------------------------------------
// S[m][j] (fp16) = Ph[m] . Ph[cidx[j]] * rnorm[cidx[j]]
// 32x32x16 fp16 MFMA (same proven structure as the round-10 deconv), BK=32,
// LDS XOR-swizzle slot = chunk ^ ((row>>1)&3). B rows gathered via cidx.
__global__ __launch_bounds__(256) void gemm_score_mfma(const f16* __restrict__ Ph,
                                                       const int* __restrict__ cidx,
                                                       const float* __restrict__ rnorm,
                                                       const int* __restrict__ nk,
                                                       f16* __restrict__ S) {
    int n0 = blockIdx.x * 128;
    if (n0 >= nk[0]) return;    // fully-masked column tile
    __shared__ f16 Ash[128 * 32], Bsh[128 * 32];
    int tid = threadIdx.x;
    int w = tid >> 6, lane = tid & 63;
    int wy = w >> 1, wx = w & 1;
    int m0 = blockIdx.y * 128;
    f32x16 acc[2][2];
#pragma unroll
    for (int mt = 0; mt < 2; ++mt)
#pragma unroll
        for (int nt = 0; nt < 2; ++nt)
#pragma unroll
            for (int e = 0; e < 16; ++e) acc[mt][nt][e] = 0.f;
    int srow = lane >> 2;                          // 0..15 staging row
    int cblk = lane & 3;                           // LDS 16B chunk slot
    int scol = (cblk ^ ((srow >> 1) & 3)) * 8;     // swizzled global col
    int dcol = cblk * 8;
    int l31 = lane & 31, kh2 = lane >> 5;
    int arow[2], brow[2], asw[2], bsw[2];
#pragma unroll
    for (int i = 0; i < 2; ++i) {
        arow[i] = wy * 64 + i * 32 + l31;
        brow[i] = wx * 64 + i * 32 + l31;
        asw[i] = (arow[i] >> 1) & 3;
        bsw[i] = (brow[i] >> 1) & 3;
    }
    const f16* Asrc[2]; const f16* Bsrc[2]; int ldso[2];
#pragma unroll
    for (int i = 0; i < 2; ++i) {
        int row = w * 32 + i * 16 + srow;
        ldso[i] = row * 32 + dcol;
        Asrc[i] = Ph + (size_t)(m0 + row) * KPAT + scol;
        Bsrc[i] = Ph + (size_t)cidx[n0 + row] * KPAT + scol;
    }
    for (int k0 = 0; k0 < KPAT; k0 += 32) {
#pragma unroll
        for (int i = 0; i < 2; ++i) {
            GLDS(Asrc[i] + k0, Ash + ldso[i]);
            GLDS(Bsrc[i] + k0, Bsh + ldso[i]);
        }
        __syncthreads();
#pragma unroll
        for (int kh = 0; kh < 2; ++kh) {
            int blk = kh * 2 + kh2;                // logical 16B chunk in row
            f16x8 va[2], vb[2];
#pragma unroll
            for (int i = 0; i < 2; ++i) {
                va[i] = *(const f16x8*)&Ash[arow[i] * 32 + ((blk ^ asw[i]) * 8)];
                vb[i] = *(const f16x8*)&Bsh[brow[i] * 32 + ((blk ^ bsw[i]) * 8)];
            }
#pragma unroll
            for (int mt = 0; mt < 2; ++mt)
#pragma unroll
                for (int nt = 0; nt < 2; ++nt)
                    acc[mt][nt] = __builtin_amdgcn_mfma_f32_32x32x16_f16(va[mt], vb[nt], acc[mt][nt], 0, 0, 0);
        }
        __syncthreads();
    }
    int rbase = 4 * kh2;
#pragma unroll
    for (int mt = 0; mt < 2; ++mt)
#pragma unroll
        for (int nt = 0; nt < 2; ++nt) {
            int col = n0 + wx * 64 + nt * 32 + l31;
            float rn = rnorm[cidx[col]];
#pragma unroll
            for (int rg = 0; rg < 16; ++rg) {
                int row = m0 + wy * 64 + mt * 32 + (rg & 3) + 8 * (rg >> 2) + rbase;
                S[(size_t)row * LPOS + col] = (f16)(acc[mt][nt][rg] * rn);
            }
        }
}

// ---------------------------------------------------------------------------
// Masked softmax over compacted columns (f16x8 reads/writes)
__global__ __launch_bounds__(256) void softmax_mask(const f16* __restrict__ S,
                                                    const int* __restrict__ nk,
                                                    const float* __restrict__ mab,
                                                    f16* __restrict__ Ah) {
    int pos = blockIdx.x;
    int tid = threadIdx.x;
    int nkeep = nk[0], kpad = nk[1];
    float ma = mab[pos];
    float sc = 10.0f * ma;
    const f16* Srow = S + (size_t)pos * LPOS;
    float v[16];
    float vmax = (nkeep < LPOS) ? 0.f : -3.0e38f;
#pragma unroll
    for (int i = 0; i < 2; ++i) {
        int jb = (tid + i * 256) * 8;
        f16x8 x8 = *(const f16x8*)(Srow + jb);
#pragma unroll
        for (int e = 0; e < 8; ++e) {
            float x = (jb + e < nkeep) ? (float)x8[e] * sc : -3.0e38f;
            v[i * 8 + e] = x;
            vmax = fmaxf(vmax, x);
        }
    }
#pragma unroll
    for (int off = 32; off; off >>= 1) vmax = fmaxf(vmax, __shfl_xor(vmax, off, 64));
    __shared__ float sred[4];
    int wid = tid >> 6;
    if ((tid & 63) == 0) sred[wid] = vmax;
    __syncthreads();
    vmax = fmaxf(fmaxf(sred[0], sred[1]), fmaxf(sred[2], sred[3]));
    __syncthreads();
    float ssum = 0.f;
#pragma unroll
    for (int i = 0; i < 16; ++i) {
        float e = (v[i] > -1.0e37f) ? __expf(v[i] - vmax) : 0.f;
        v[i] = e;
        ssum += e;
    }
#pragma unroll
    for (int off = 32; off; off >>= 1) ssum += __shfl_xor(ssum, off, 64);
    if ((tid & 63) == 0) sred[wid] = ssum;
    __syncthreads();
    float total = sred[0] + sred[1] + sred[2] + sred[3]
                + (float)(LPOS - nkeep) * __expf(-vmax);
    float inv = 1.f / total;
#pragma unroll
    for (int i = 0; i < 2; ++i) {
        int jb = (tid + i * 256) * 8;
        if (jb >= kpad) continue;
        f16x8 h;
#pragma unroll
        for (int e = 0; e < 8; ++e)
            h[e] = (jb + e < nkeep) ? (f16)(v[i * 8 + e] * inv * ma) : (f16)0.f;
        *(f16x8*)(Ah + (size_t)pos * LPOS + jb) = h;
    }
}

// ---------------------------------------------------------------------------
// Rt[n][j] fp16, n = (t*4+s)*128 + c, patch p = cidx[j] (compacted gather)
__global__ __launch_bounds__(256) void build_Rt(const float* __restrict__ x1b,
                                                const int* __restrict__ cidx,
                                                const int* __restrict__ nk,
                                                f16* __restrict__ Rt) {
    int idx = blockIdx.x * 256 + threadIdx.x;   // n*4096 + j
    int j = idx & 4095, n = idx >> 12;
    if (j >= nk[1]) return;
    int p = cidx[j];
    int pu = p >> 6, pv = p & 63;
    int t = (n >> 9) & 3, s = (n >> 7) & 3, c = n & 127;
    int yy = 2 * pu - 1 + t, xx = 2 * pv - 1 + s;
    float val = 0.f;
    if (yy >= 0 && yy < 128 && xx >= 0 && xx < 128)
        val = x1b[c * 16384 + yy * 128 + xx];
    Rt[idx] = (f16)val;
}

// ---------------------------------------------------------------------------
// V[m][n] = sum_{k<kpad} A[m][k] * Bt[n][k]   (32x32x16 fp16 MFMA, fp16 out)
// Round-10 proven version: BK=32, XOR swizzle, XCD m-grouping.
__global__ __launch_bounds__(256) void gemm_deconv_mfma(const f16* __restrict__ A,
                                                        const f16* __restrict__ Bt,
                                                        const int* __restrict__ nk,
                                                        f16* __restrict__ V) {
    __shared__ f16 Ash[128 * 32], Bsh[128 * 32];
    int kpad = nk[1];
    int id = blockIdx.x;
    int m0 = ((id & 7) * 4 + ((id >> 3) & 3)) * 128;
    int n0 = (id >> 5) * 128;
    int tid = threadIdx.x;
    int w = tid >> 6, lane = tid & 63;
    int wy = w >> 1, wx = w & 1;
    f32x16 acc[2][2];
#pragma unroll
    for (int mt = 0; mt < 2; ++mt)
#pragma unroll
        for (int nt = 0; nt < 2; ++nt)
#pragma unroll
            for (int e = 0; e < 16; ++e) acc[mt][nt][e] = 0.f;
    int srow = lane >> 2;
    int cblk = lane & 3;
    int scol = (cblk ^ ((srow >> 1) & 3)) * 8;
    int dcol = cblk * 8;
    int l31 = lane & 31, kh2 = lane >> 5;
    int arow[2], brow[2], asw[2], bsw[2];
#pragma unroll
    for (int i = 0; i < 2; ++i) {
        arow[i] = wy * 64 + i * 32 + l31;
        brow[i] = wx * 64 + i * 32 + l31;
        asw[i] = (arow[i] >> 1) & 3;
        bsw[i] = (brow[i] >> 1) & 3;
    }
    for (int k0 = 0; k0 < kpad; k0 += 32) {
#pragma unroll
        for (int i = 0; i < 2; ++i) {
            int row = w * 32 + i * 16 + srow;
            int ldso = row * 32 + dcol;
            GLDS(A + (size_t)(m0 + row) * LPOS + k0 + scol, Ash + ldso);
            GLDS(Bt + (size_t)(n0 + row) * LPOS + k0 + scol, Bsh + ldso);
        }
        __syncthreads();
#pragma unroll
        for (int kh = 0; kh < 2; ++kh) {
            int blk = kh * 2 + kh2;                // logical 16B block in row
            f16x8 va[2], vb[2];
#pragma unroll
            for (int i = 0; i < 2; ++i) {
                va[i] = *(const f16x8*)&Ash[arow[i] * 32 + ((blk ^ asw[i]) * 8)];
                vb[i] = *(const f16x8*)&Bsh[brow[i] * 32 + ((blk ^ bsw[i]) * 8)];
            }
#pragma unroll
            for (int mt = 0; mt < 2; ++mt)
#pragma unroll
                for (int nt = 0; nt < 2; ++nt)
                    acc[mt][nt] = __builtin_amdgcn_mfma_f32_32x32x16_f16(va[mt], vb[nt], acc[mt][nt], 0, 0, 0);
        }
        __syncthreads();
    }
    int rbase = 4 * kh2;
#pragma unroll
    for (int mt = 0; mt < 2; ++mt)
#pragma unroll
        for (int nt = 0; nt < 2; ++nt) {
            int col = n0 + wx * 64 + nt * 32 + l31;
#pragma unroll
            for (int rg = 0; rg < 16; ++rg) {
                int row = m0 + wy * 64 + mt * 32 + (rg & 3) + 8 * (rg >> 2) + rbase;
                V[(size_t)row * RPAT + col] = (f16)acc[mt][nt][rg];
            }
        }
}

// ---------------------------------------------------------------------------
// reconstruct -> chunk-major padded layout:
// ybTp[b][yy+8][q=c>>3][xx+8][c&7] = 0.25 * sum over valid taps of V
__global__ __launch_bounds__(256) void reconstruct(const f16* __restrict__ V,
                                                   f16* __restrict__ ybTpb) {
    int idx = blockIdx.x * 256 + threadIdx.x;   // p*128 + c
    int c = idx & 127, p = idx >> 7;
    int xx = p & 127, yy = p >> 7;
    float sum = 0.f;
    int tby = (yy & 1) ? 0 : 1;
    int tbx = (xx & 1) ? 0 : 1;
#pragma unroll
    for (int dt = 0; dt < 2; ++dt) {
        int t = tby + 2 * dt;
        int u2 = yy + 1 - t;
        if (u2 < 0 || u2 >= 128) continue;
        int u = u2 >> 1;
#pragma unroll
        for (int ds = 0; ds < 2; ++ds) {
            int s = tbx + 2 * ds;
            int v2 = xx + 1 - s;
            if (v2 < 0 || v2 >= 128) continue;
            int v = v2 >> 1;
            sum += (float)V[(size_t)(u * 64 + v) * RPAT + (t * 4 + s) * 128 + c];
        }
    }
    ybTpb[(size_t)(yy + 8) * ROWS + (c >> 3) * 1152 + (xx + 8) * 8 + (c & 7)] = (f16)(0.25f * sum);
}

// ---------------------------------------------------------------------------
// Wt[g][tap][oc][c] fp16 from conv_w (4,16,128,3,3) fp32
__global__ __launch_bounds__(256) void prep_w(const float* __restrict__ cw,
                                              f16* __restrict__ Wt) {
    int idx = blockIdx.x * 256 + threadIdx.x;
    if (idx >= 4 * 9 * 16 * 128) return;
    int g = idx / 18432, rem = idx % 18432;
    int tap = rem >> 11, oc = (rem >> 7) & 15, c = rem & 127;
    Wt[idx] = (f16)cw[(((g * 16 + oc) * 128 + c) * 9) + tap];
}

// ---------------------------------------------------------------------------
// Tap-decomposed implicit-GEMM grouped dilated conv via MFMA (fp16).
__global__ __launch_bounds__(256) void final_conv_mfma(const f16* __restrict__ ybTp,
                                                       const f16* __restrict__ Wt,
                                                       const float* __restrict__ cb,
                                                       float* __restrict__ out) {
    int id = blockIdx.x;
    int p = id & 7;
    int b = p >> 1, yhalf = p & 1;
    int rest = id >> 3;             // 0..255
    int g = rest >> 6;              // 0..3
    int y = yhalf * 64 + (rest & 63);
    int tid = threadIdx.x, w = tid >> 6, lane = tid & 63;
    int xbase = w * 32;
    int r = 1 << g;                 // RATES = 1,2,4,8
    int m = lane & 15, q = lane >> 4;
    const f16* yB = ybTp + (size_t)b * PPAD * 128;
    const f16* Wg = Wt + g * 18432 + m * 128 + q * 8;
    f32x4 acc[2];
    acc[0] = (f32x4){0.f, 0.f, 0.f, 0.f};
    acc[1] = (f32x4){0.f, 0.f, 0.f, 0.f};
#pragma unroll
    for (int tap = 0; tap < 9; ++tap) {
        int dy = (tap / 3 - 1) * r, dx = (tap % 3 - 1) * r;
        const f16* rowb = yB + (size_t)(y + dy + 8) * ROWS + q * 1152
                        + (xbase + m + 8 + dx) * 8;
        const f16* wrow = Wg + tap * 2048;
#pragma unroll
        for (int ks = 0; ks < 4; ++ks) {
            f16x8 bfrag = *(const f16x8*)(wrow + ks * 32);
            f16x8 a0 = *(const f16x8*)(rowb + ks * 4608);
            f16x8 a1 = *(const f16x8*)(rowb + ks * 4608 + 128);
            acc[0] = __builtin_amdgcn_mfma_f32_16x16x32_f16(a0, bfrag, acc[0], 0, 0, 0);
            acc[1] = __builtin_amdgcn_mfma_f32_16x16x32_f16(a1, bfrag, acc[1], 0, 0, 0);
        }
    }
    float bias = cb[g * 16 + m];
    float* orow = out + ((size_t)(b * 64 + g * 16 + m)) * 16384 + (size_t)y * 128;
#pragma unroll
    for (int mt = 0; mt < 2; ++mt)
#pragma unroll
        for (int ri = 0; ri < 4; ++ri) {
            int x = xbase + mt * 16 + q * 4 + ri;
            orow[x] = fmaxf(acc[mt][ri] + bias, 0.f);
        }
}

// ---------------------------------------------------------------------------
extern "C" void kernel_launch(void* const* d_in, const int* in_sizes, int n_in,
                              void* d_out, int out_size, void* d_ws, size_t ws_size,
                              hipStream_t stream) {
    const float* x1 = (const float*)d_in[0];        // (4,128,128,128)
    const float* x2 = (const float*)d_in[1];        // (4,64,64,64)
    const float* mask = (const float*)d_in[2];      // (4,1,128,128)
    const float* mask_all = (const float*)d_in[3];  // (4,1,64,64)
    const float* conv_w = (const float*)d_in[4];    // (4,16,128,3,3)
    const float* conv_b = (const float*)d_in[5];    // (4,16)
    float* out = (float*)d_out;                     // (4,64,128,128)

    char* ws = (char*)d_ws;
    f16*   Ph    = (f16*)  (ws + 0);            //  4,718,592 B
    float* rnorm = (float*)(ws + 4718592);      //     16,384 B
    int*   cidx  = (int*)  (ws + 4734976);      //     69,632 B (4 batches)
    int*   nk    = (int*)  (ws + 4804608);      //         32 B
    f16*   S     = (f16*)  (ws + 9469952);      // 33,554,432 B (fp16 scores)
    f16*   V     = (f16*)  (ws + 43024384);     // 16,777,216 B
    f16*   Ah    = (f16*)  (ws + 76578816);     // 33,554,432 B
    f16*   Rt    = (f16*)  (ws + 110133248);    // 16,777,216 B
    f16*   ybTp  = (f16*)  (ws + 126910464);    // 21,233,664 B (padded, 4 batches)
    f16*   Wt    = (f16*)  (ws + 148144128);    //     73,728 B (end 148,217,856)

    prep_w<<<288, 256, 0, stream>>>(conv_w, Wt);
    compact_mask_all<<<4, 256, 0, stream>>>(mask, cidx, nk);
    zero_halo<<<5184, 256, 0, stream>>>(ybTp);
    for (int b = 0; b < 4; ++b) {
        const float* x2b = x2 + (size_t)b * 64 * 4096;
        const float* x1b = x1 + (size_t)b * 128 * 16384;
        const int* cb_idx = cidx + b * 4352;
        const int* nkb = nk + b * 2;
        build_P_norm<<<4096, 64, 0, stream>>>(x2b, Ph, rnorm);
        gemm_score_mfma<<<dim3(32, 32), 256, 0, stream>>>(Ph, cb_idx, rnorm, nkb, S);
        softmax_mask<<<4096, 256, 0, stream>>>(S, nkb, mask_all + (size_t)b * 4096, Ah);
        build_Rt<<<32768, 256, 0, stream>>>(x1b, cb_idx, nkb, Rt);
        gemm_deconv_mfma<<<512, 256, 0, stream>>>(Ah, Rt, nkb, V);
        reconstruct<<<8192, 256, 0, stream>>>(V, ybTp + (size_t)b * PPAD * 128);
    }
    final_conv_mfma<<<2048, 256, 0, stream>>>(ybTp, Wt, conv_b, out);
}

// Round 13
// 679.137 us; speedup vs baseline: 1.0484x; 1.0484x over previous
//
#include <hip/hip_runtime.h>
#include <math.h>

typedef _Float16 f16;
typedef __attribute__((ext_vector_type(8))) _Float16 f16x8;
typedef __attribute__((ext_vector_type(4))) float f32x4;
typedef __attribute__((ext_vector_type(16))) float f32x16;

#define LPOS 4096      // 64*64 positions / patches
#define KPAT 576       // 64ch * 3*3 patch
#define RPAT 2048      // 128ch * 4*4 raw patch
#define PPAD 20736     // 144*144 padded positions for ybT
#define ROWS 18432     // elems per padded row: 16 chunks * 144 x * 8

#define GLDS(g, l) __builtin_amdgcn_global_load_lds( \
    (const __attribute__((address_space(1))) void*)(g), \
    (__attribute__((address_space(3))) void*)(l), 16, 0, 0)

// ---------------------------------------------------------------------------
// Ph[pos][576] = fp16 3x3x64 patches of x2[b] (zero pad 1); rnorm[pos]
__global__ __launch_bounds__(64) void build_P_norm(const float* __restrict__ x2b,
                                                   f16* __restrict__ Ph,
                                                   float* __restrict__ rnorm) {
    int pos = blockIdx.x;
    int u = pos >> 6, v = pos & 63;
    int tid = threadIdx.x;
    float ss = 0.f;
    for (int k = tid; k < KPAT; k += 64) {
        int c = k / 9, r9 = k % 9;
        int di = r9 / 3, dj = r9 % 3;
        int yy = u + di - 1, xx = v + dj - 1;
        float val = 0.f;
        if (yy >= 0 && yy < 64 && xx >= 0 && xx < 64)
            val = x2b[c * 4096 + yy * 64 + xx];
        Ph[pos * KPAT + k] = (f16)val;
        ss += val * val;
    }
#pragma unroll
    for (int off = 32; off; off >>= 1) ss += __shfl_xor(ss, off, 64);
    if (tid == 0) rnorm[pos] = 1.f / fmaxf(sqrtf(ss), 1e-4f);
}

// ---------------------------------------------------------------------------
// All 4 batches in one launch: block b compacts mask[b] -> cidx[b], nk[b]
// nk[0] = nkeep, nk[1] = nkeep padded to 64 (deconv BK)
__global__ __launch_bounds__(256) void compact_mask_all(const float* __restrict__ mask,
                                                        int* __restrict__ cidx_all,
                                                        int* __restrict__ nk_all) {
    int b = blockIdx.x;
    const float* maskb = mask + (size_t)b * 16384;
    int* cidx = cidx_all + b * 4352;
    int* nk = nk_all + b * 2;
    int tid = threadIdx.x;
    int keep[16];
    int cnt = 0;
#pragma unroll
    for (int e = 0; e < 16; ++e) {
        int pos = tid * 16 + e;
        int pu = pos >> 6, pv = pos & 63;
        float s = 0.f;
        for (int t = 0; t < 4; ++t)
            for (int w = 0; w < 4; ++w) {
                int yy = 2 * pu - 1 + t, xx = 2 * pv - 1 + w;
                if (yy >= 0 && yy < 128 && xx >= 0 && xx < 128)
                    s += maskb[yy * 128 + xx];
            }
        keep[e] = (s == 0.f) ? 1 : 0;
        cnt += keep[e];
    }
    __shared__ int ps[256];
    ps[tid] = cnt;
    __syncthreads();
    for (int off = 1; off < 256; off <<= 1) {
        int v = (tid >= off) ? ps[tid - off] : 0;
        __syncthreads();
        ps[tid] += v;
        __syncthreads();
    }
    int total = ps[255];
    int base = ps[tid] - cnt;   // exclusive prefix
#pragma unroll
    for (int e = 0; e < 16; ++e)
        if (keep[e]) cidx[base++] = tid * 16 + e;
    for (int i = total + tid; i < 4352; i += 256) cidx[i] = 0;
    if (tid == 0) { nk[0] = total; nk[1] = (total + 63) & ~63; }
}

// ---------------------------------------------------------------------------
// Zero the 8-wide halo of the padded chunk-major ybT buffer (all 4 batches)
__global__ __launch_bounds__(256) void zero_halo(f16* __restrict__ ybTp) {
    int idx = blockIdx.x * 256 + threadIdx.x;
    int b = idx / 331776; if (b >= 4) return;
    int rem = idx % 331776;                     // 144*144*16
    int q = rem & 15, pos = rem >> 4;
    int yy = pos / 144, xx = pos % 144;
    if (yy >= 8 && yy < 136 && xx >= 8 && xx < 136) return;
    *(f16x8*)(ybTp + (size_t)b * PPAD * 128 + (size_t)yy * ROWS + q * 1152 + xx * 8) = (f16x8){};
}

// ---------------------------------------------------------------------------
// S[m][j] (fp16) = Ph[m] . Ph[cidx[j]] * rnorm[cidx[j]]
// 32x32x16 fp16 MFMA, BK=32, LDS XOR-swizzle slot = chunk ^ ((row>>1)&3).
__global__ __launch_bounds__(256) void gemm_score_mfma(const f16* __restrict__ Ph,
                                                       const int* __restrict__ cidx,
                                                       const float* __restrict__ rnorm,
                                                       const int* __restrict__ nk,
                                                       f16* __restrict__ S) {
    int n0 = blockIdx.x * 128;
    if (n0 >= nk[0]) return;    // fully-masked column tile
    __shared__ f16 Ash[128 * 32], Bsh[128 * 32];
    int tid = threadIdx.x;
    int w = tid >> 6, lane = tid & 63;
    int wy = w >> 1, wx = w & 1;
    int m0 = blockIdx.y * 128;
    f32x16 acc[2][2];
#pragma unroll
    for (int mt = 0; mt < 2; ++mt)
#pragma unroll
        for (int nt = 0; nt < 2; ++nt)
#pragma unroll
            for (int e = 0; e < 16; ++e) acc[mt][nt][e] = 0.f;
    int srow = lane >> 2;                          // 0..15 staging row
    int cblk = lane & 3;                           // LDS 16B chunk slot
    int scol = (cblk ^ ((srow >> 1) & 3)) * 8;     // swizzled global col
    int dcol = cblk * 8;
    int l31 = lane & 31, kh2 = lane >> 5;
    int arow[2], brow[2], asw[2], bsw[2];
#pragma unroll
    for (int i = 0; i < 2; ++i) {
        arow[i] = wy * 64 + i * 32 + l31;
        brow[i] = wx * 64 + i * 32 + l31;
        asw[i] = (arow[i] >> 1) & 3;
        bsw[i] = (brow[i] >> 1) & 3;
    }
    const f16* Asrc[2]; const f16* Bsrc[2]; int ldso[2];
#pragma unroll
    for (int i = 0; i < 2; ++i) {
        int row = w * 32 + i * 16 + srow;
        ldso[i] = row * 32 + dcol;
        Asrc[i] = Ph + (size_t)(m0 + row) * KPAT + scol;
        Bsrc[i] = Ph + (size_t)cidx[n0 + row] * KPAT + scol;
    }
    for (int k0 = 0; k0 < KPAT; k0 += 32) {
#pragma unroll
        for (int i = 0; i < 2; ++i) {
            GLDS(Asrc[i] + k0, Ash + ldso[i]);
            GLDS(Bsrc[i] + k0, Bsh + ldso[i]);
        }
        __syncthreads();
#pragma unroll
        for (int kh = 0; kh < 2; ++kh) {
            int blk = kh * 2 + kh2;                // logical 16B chunk in row
            f16x8 va[2], vb[2];
#pragma unroll
            for (int i = 0; i < 2; ++i) {
                va[i] = *(const f16x8*)&Ash[arow[i] * 32 + ((blk ^ asw[i]) * 8)];
                vb[i] = *(const f16x8*)&Bsh[brow[i] * 32 + ((blk ^ bsw[i]) * 8)];
            }
#pragma unroll
            for (int mt = 0; mt < 2; ++mt)
#pragma unroll
                for (int nt = 0; nt < 2; ++nt)
                    acc[mt][nt] = __builtin_amdgcn_mfma_f32_32x32x16_f16(va[mt], vb[nt], acc[mt][nt], 0, 0, 0);
        }
        __syncthreads();
    }
    int rbase = 4 * kh2;
#pragma unroll
    for (int mt = 0; mt < 2; ++mt)
#pragma unroll
        for (int nt = 0; nt < 2; ++nt) {
            int col = n0 + wx * 64 + nt * 32 + l31;
            float rn = rnorm[cidx[col]];
#pragma unroll
            for (int rg = 0; rg < 16; ++rg) {
                int row = m0 + wy * 64 + mt * 32 + (rg & 3) + 8 * (rg >> 2) + rbase;
                S[(size_t)row * LPOS + col] = (f16)(acc[mt][nt][rg] * rn);
            }
        }
}

// ---------------------------------------------------------------------------
// Masked softmax over compacted columns (f16x8 reads/writes)
__global__ __launch_bounds__(256) void softmax_mask(const f16* __restrict__ S,
                                                    const int* __restrict__ nk,
                                                    const float* __restrict__ mab,
                                                    f16* __restrict__ Ah) {
    int pos = blockIdx.x;
    int tid = threadIdx.x;
    int nkeep = nk[0], kpad = nk[1];
    float ma = mab[pos];
    float sc = 10.0f * ma;
    const f16* Srow = S + (size_t)pos * LPOS;
    float v[16];
    float vmax = (nkeep < LPOS) ? 0.f : -3.0e38f;
#pragma unroll
    for (int i = 0; i < 2; ++i) {
        int jb = (tid + i * 256) * 8;
        f16x8 x8 = *(const f16x8*)(Srow + jb);
#pragma unroll
        for (int e = 0; e < 8; ++e) {
            float x = (jb + e < nkeep) ? (float)x8[e] * sc : -3.0e38f;
            v[i * 8 + e] = x;
            vmax = fmaxf(vmax, x);
        }
    }
#pragma unroll
    for (int off = 32; off; off >>= 1) vmax = fmaxf(vmax, __shfl_xor(vmax, off, 64));
    __shared__ float sred[4];
    int wid = tid >> 6;
    if ((tid & 63) == 0) sred[wid] = vmax;
    __syncthreads();
    vmax = fmaxf(fmaxf(sred[0], sred[1]), fmaxf(sred[2], sred[3]));
    __syncthreads();
    float ssum = 0.f;
#pragma unroll
    for (int i = 0; i < 16; ++i) {
        float e = (v[i] > -1.0e37f) ? __expf(v[i] - vmax) : 0.f;
        v[i] = e;
        ssum += e;
    }
#pragma unroll
    for (int off = 32; off; off >>= 1) ssum += __shfl_xor(ssum, off, 64);
    if ((tid & 63) == 0) sred[wid] = ssum;
    __syncthreads();
    float total = sred[0] + sred[1] + sred[2] + sred[3]
                + (float)(LPOS - nkeep) * __expf(-vmax);
    float inv = 1.f / total;
#pragma unroll
    for (int i = 0; i < 2; ++i) {
        int jb = (tid + i * 256) * 8;
        if (jb >= kpad) continue;
        f16x8 h;
#pragma unroll
        for (int e = 0; e < 8; ++e)
            h[e] = (jb + e < nkeep) ? (f16)(v[i * 8 + e] * inv * ma) : (f16)0.f;
        *(f16x8*)(Ah + (size_t)pos * LPOS + jb) = h;
    }
}

// ---------------------------------------------------------------------------
// Rt[n][j] fp16, n = (t*4+s)*128 + c, patch p = cidx[j] (compacted gather)
__global__ __launch_bounds__(256) void build_Rt(const float* __restrict__ x1b,
                                                const int* __restrict__ cidx,
                                                const int* __restrict__ nk,
                                                f16* __restrict__ Rt) {
    int idx = blockIdx.x * 256 + threadIdx.x;   // n*4096 + j
    int j = idx & 4095, n = idx >> 12;
    if (j >= nk[1]) return;
    int p = cidx[j];
    int pu = p >> 6, pv = p & 63;
    int t = (n >> 9) & 3, s = (n >> 7) & 3, c = n & 127;
    int yy = 2 * pu - 1 + t, xx = 2 * pv - 1 + s;
    float val = 0.f;
    if (yy >= 0 && yy < 128 && xx >= 0 && xx < 128)
        val = x1b[c * 16384 + yy * 128 + xx];
    Rt[idx] = (f16)val;
}

// ---------------------------------------------------------------------------
// V[m][n] = sum_{k<kpad} A[m][k] * Bt[n][k]   (32x32x16 fp16 MFMA, fp16 out)
// BK=64: rows are 128 B; slot = chunk ^ (row&7). Halves barrier-drain events
// vs BK=32. 1D grid 512: XCD (id&7) owns 4 m-tiles -> A slice L2-resident.
__global__ __launch_bounds__(256) void gemm_deconv_mfma(const f16* __restrict__ A,
                                                        const f16* __restrict__ Bt,
                                                        const int* __restrict__ nk,
                                                        f16* __restrict__ V) {
    __shared__ f16 Ash[128 * 64], Bsh[128 * 64];
    int kpad = nk[1];
    int id = blockIdx.x;
    int m0 = ((id & 7) * 4 + ((id >> 3) & 3)) * 128;
    int n0 = (id >> 5) * 128;
    int tid = threadIdx.x;
    int w = tid >> 6, lane = tid & 63;
    int wy = w >> 1, wx = w & 1;
    f32x16 acc[2][2];
#pragma unroll
    for (int mt = 0; mt < 2; ++mt)
#pragma unroll
        for (int nt = 0; nt < 2; ++nt)
#pragma unroll
            for (int e = 0; e < 16; ++e) acc[mt][nt][e] = 0.f;
    int srow = lane >> 3;          // 0..7 staging row within instr
    int cblk = lane & 7;           // 0..7 LDS slot (16B chunk) within row
    int scol = (cblk ^ srow) * 8;  // swizzled global chunk (f(row) = row&7 = srow)
    int l31 = lane & 31, kh2 = lane >> 5;
    int f7 = l31 & 7;              // read-side f(row)
    int arow[2], brow[2];
#pragma unroll
    for (int i = 0; i < 2; ++i) {
        arow[i] = wy * 64 + i * 32 + l31;
        brow[i] = wx * 64 + i * 32 + l31;
    }
    for (int k0 = 0; k0 < kpad; k0 += 64) {
#pragma unroll
        for (int i = 0; i < 4; ++i) {
            int row = w * 32 + i * 8 + srow;
            int ldso = row * 64 + cblk * 8;
            GLDS(A + (size_t)(m0 + row) * LPOS + k0 + scol, Ash + ldso);
            GLDS(Bt + (size_t)(n0 + row) * LPOS + k0 + scol, Bsh + ldso);
        }
        __syncthreads();
#pragma unroll
        for (int kh = 0; kh < 4; ++kh) {
            int slot = (kh * 2 + kh2) ^ f7;
            f16x8 va[2], vb[2];
#pragma unroll
            for (int i = 0; i < 2; ++i) {
                va[i] = *(const f16x8*)&Ash[arow[i] * 64 + slot * 8];
                vb[i] = *(const f16x8*)&Bsh[brow[i] * 64 + slot * 8];
            }
#pragma unroll
            for (int mt = 0; mt < 2; ++mt)
#pragma unroll
                for (int nt = 0; nt < 2; ++nt)
                    acc[mt][nt] = __builtin_amdgcn_mfma_f32_32x32x16_f16(va[mt], vb[nt], acc[mt][nt], 0, 0, 0);
        }
        __syncthreads();
    }
    int rbase = 4 * kh2;
#pragma unroll
    for (int mt = 0; mt < 2; ++mt)
#pragma unroll
        for (int nt = 0; nt < 2; ++nt) {
            int col = n0 + wx * 64 + nt * 32 + l31;
#pragma unroll
            for (int rg = 0; rg < 16; ++rg) {
                int row = m0 + wy * 64 + mt * 32 + (rg & 3) + 8 * (rg >> 2) + rbase;
                V[(size_t)row * RPAT + col] = (f16)acc[mt][nt][rg];
            }
        }
}

// ---------------------------------------------------------------------------
// reconstruct -> chunk-major padded layout:
// ybTp[b][yy+8][q=c>>3][xx+8][c&7] = 0.25 * sum over valid taps of V
__global__ __launch_bounds__(256) void reconstruct(const f16* __restrict__ V,
                                                   f16* __restrict__ ybTpb) {
    int idx = blockIdx.x * 256 + threadIdx.x;   // p*128 + c
    int c = idx & 127, p = idx >> 7;
    int xx = p & 127, yy = p >> 7;
    float sum = 0.f;
    int tby = (yy & 1) ? 0 : 1;
    int tbx = (xx & 1) ? 0 : 1;
#pragma unroll
    for (int dt = 0; dt < 2; ++dt) {
        int t = tby + 2 * dt;
        int u2 = yy + 1 - t;
        if (u2 < 0 || u2 >= 128) continue;
        int u = u2 >> 1;
#pragma unroll
        for (int ds = 0; ds < 2; ++ds) {
            int s = tbx + 2 * ds;
            int v2 = xx + 1 - s;
            if (v2 < 0 || v2 >= 128) continue;
            int v = v2 >> 1;
            sum += (float)V[(size_t)(u * 64 + v) * RPAT + (t * 4 + s) * 128 + c];
        }
    }
    ybTpb[(size_t)(yy + 8) * ROWS + (c >> 3) * 1152 + (xx + 8) * 8 + (c & 7)] = (f16)(0.25f * sum);
}

// ---------------------------------------------------------------------------
// Wt[g][tap][oc][c] fp16 from conv_w (4,16,128,3,3) fp32
__global__ __launch_bounds__(256) void prep_w(const float* __restrict__ cw,
                                              f16* __restrict__ Wt) {
    int idx = blockIdx.x * 256 + threadIdx.x;
    if (idx >= 4 * 9 * 16 * 128) return;
    int g = idx / 18432, rem = idx % 18432;
    int tap = rem >> 11, oc = (rem >> 7) & 15, c = rem & 127;
    Wt[idx] = (f16)cw[(((g * 16 + oc) * 128 + c) * 9) + tap];
}

// ---------------------------------------------------------------------------
// Tap-decomposed implicit-GEMM grouped dilated conv via MFMA (fp16).
__global__ __launch_bounds__(256) void final_conv_mfma(const f16* __restrict__ ybTp,
                                                       const f16* __restrict__ Wt,
                                                       const float* __restrict__ cb,
                                                       float* __restrict__ out) {
    int id = blockIdx.x;
    int p = id & 7;
    int b = p >> 1, yhalf = p & 1;
    int rest = id >> 3;             // 0..255
    int g = rest >> 6;              // 0..3
    int y = yhalf * 64 + (rest & 63);
    int tid = threadIdx.x, w = tid >> 6, lane = tid & 63;
    int xbase = w * 32;
    int r = 1 << g;                 // RATES = 1,2,4,8
    int m = lane & 15, q = lane >> 4;
    const f16* yB = ybTp + (size_t)b * PPAD * 128;
    const f16* Wg = Wt + g * 18432 + m * 128 + q * 8;
    f32x4 acc[2];
    acc[0] = (f32x4){0.f, 0.f, 0.f, 0.f};
    acc[1] = (f32x4){0.f, 0.f, 0.f, 0.f};
#pragma unroll
    for (int tap = 0; tap < 9; ++tap) {
        int dy = (tap / 3 - 1) * r, dx = (tap % 3 - 1) * r;
        const f16* rowb = yB + (size_t)(y + dy + 8) * ROWS + q * 1152
                        + (xbase + m + 8 + dx) * 8;
        const f16* wrow = Wg + tap * 2048;
#pragma unroll
        for (int ks = 0; ks < 4; ++ks) {
            f16x8 bfrag = *(const f16x8*)(wrow + ks * 32);
            f16x8 a0 = *(const f16x8*)(rowb + ks * 4608);
            f16x8 a1 = *(const f16x8*)(rowb + ks * 4608 + 128);
            acc[0] = __builtin_amdgcn_mfma_f32_16x16x32_f16(a0, bfrag, acc[0], 0, 0, 0);
            acc[1] = __builtin_amdgcn_mfma_f32_16x16x32_f16(a1, bfrag, acc[1], 0, 0, 0);
        }
    }
    float bias = cb[g * 16 + m];
    float* orow = out + ((size_t)(b * 64 + g * 16 + m)) * 16384 + (size_t)y * 128;
#pragma unroll
    for (int mt = 0; mt < 2; ++mt)
#pragma unroll
        for (int ri = 0; ri < 4; ++ri) {
            int x = xbase + mt * 16 + q * 4 + ri;
            orow[x] = fmaxf(acc[mt][ri] + bias, 0.f);
        }
}

// ---------------------------------------------------------------------------
extern "C" void kernel_launch(void* const* d_in, const int* in_sizes, int n_in,
                              void* d_out, int out_size, void* d_ws, size_t ws_size,
                              hipStream_t stream) {
    const float* x1 = (const float*)d_in[0];        // (4,128,128,128)
    const float* x2 = (const float*)d_in[1];        // (4,64,64,64)
    const float* mask = (const float*)d_in[2];      // (4,1,128,128)
    const float* mask_all = (const float*)d_in[3];  // (4,1,64,64)
    const float* conv_w = (const float*)d_in[4];    // (4,16,128,3,3)
    const float* conv_b = (const float*)d_in[5];    // (4,16)
    float* out = (float*)d_out;                     // (4,64,128,128)

    char* ws = (char*)d_ws;
    f16*   Ph    = (f16*)  (ws + 0);            //  4,718,592 B
    float* rnorm = (float*)(ws + 4718592);      //     16,384 B
    int*   cidx  = (int*)  (ws + 4734976);      //     69,632 B (4 batches)
    int*   nk    = (int*)  (ws + 4804608);      //         32 B
    f16*   S     = (f16*)  (ws + 9469952);      // 33,554,432 B (fp16 scores)
    f16*   V     = (f16*)  (ws + 43024384);     // 16,777,216 B
    f16*   Ah    = (f16*)  (ws + 76578816);     // 33,554,432 B
    f16*   Rt    = (f16*)  (ws + 110133248);    // 16,777,216 B
    f16*   ybTp  = (f16*)  (ws + 126910464);    // 21,233,664 B (padded, 4 batches)
    f16*   Wt    = (f16*)  (ws + 148144128);    //     73,728 B (end 148,217,856)

    prep_w<<<288, 256, 0, stream>>>(conv_w, Wt);
    compact_mask_all<<<4, 256, 0, stream>>>(mask, cidx, nk);
    zero_halo<<<5184, 256, 0, stream>>>(ybTp);
    for (int b = 0; b < 4; ++b) {
        const float* x2b = x2 + (size_t)b * 64 * 4096;
        const float* x1b = x1 + (size_t)b * 128 * 16384;
        const int* cb_idx = cidx + b * 4352;
        const int* nkb = nk + b * 2;
        build_P_norm<<<4096, 64, 0, stream>>>(x2b, Ph, rnorm);
        gemm_score_mfma<<<dim3(32, 32), 256, 0, stream>>>(Ph, cb_idx, rnorm, nkb, S);
        softmax_mask<<<4096, 256, 0, stream>>>(S, nkb, mask_all + (size_t)b * 4096, Ah);
        build_Rt<<<32768, 256, 0, stream>>>(x1b, cb_idx, nkb, Rt);
        gemm_deconv_mfma<<<512, 256, 0, stream>>>(Ah, Rt, nkb, V);
        reconstruct<<<8192, 256, 0, stream>>>(V, ybTp + (size_t)b * PPAD * 128);
    }
    final_conv_mfma<<<2048, 256, 0, stream>>>(ybTp, Wt, conv_b, out);
}